// Round 11
// baseline (573.822 us; speedup 1.0000x reference)
//
#include <hip/hip_runtime.h>

// TypeAwareEdgeUpdate: out = relu(relu(cat[n1@W1[t1]+b1, n2@W2[t2]+b2, e@We+be]) @ Wout + bout)
// Counting-sort rows by (t1,t2) -> 64-row tiles share weights -> fused bf16 MFMA.
// R11 = R7 inner structure (proven 290us) + persistent 512-block grid:
//   - each block owns a contiguous chunk of tiles (XCD-chunked -> weight L1/L2 reuse,
//     same-pair runs ~10 tiles stay on one CU)
//   - next tile's n1 prefetched in the register-free window (issue@X2 h0 / write@Y3,
//     issue h1 before epilogue / write after) -> per-tile exposed stage eliminated
//   - srow ping-pong [2][64]

#define J_TYPES 17
#define PAIRS   (J_TYPES * J_TYPES)
#define DN      256
#define DE      128
#define DO      256
#define TILE    64
#define LDA     264   // ldsA / ldsT stride (shorts) for 256 cols
#define LDE     136   // ldsA stride for K=128 (edge path)
#define NBLK    512   // persistent blocks = 2 per CU

typedef short bf16x8 __attribute__((ext_vector_type(8)));
typedef float f32x4  __attribute__((ext_vector_type(4)));

// LDS-only barrier: wait LDS ops, let VMEM (stage prefetch) stay in flight.
#define BAR() asm volatile("s_waitcnt lgkmcnt(0)\n\ts_barrier" ::: "memory")

__device__ __forceinline__ unsigned short f2bf(float x) {
  unsigned u = __float_as_uint(x);
  return (unsigned short)((u + 0x7fffu + ((u >> 16) & 1u)) >> 16);  // RNE
}

__device__ __forceinline__ unsigned cvtpk(float lo, float hi) {
  unsigned r;
  asm("v_cvt_pk_bf16_f32 %0, %1, %2" : "=v"(r) : "v"(lo), "v"(hi));
  return r;  // lo16 = bf16(lo), hi16 = bf16(hi), RNE
}

// ---------------- weight prep: bf16, fragment-native layout ----------------
// Layout per matrix: [colt][k32][lane][i] (shorts), element (col,k):
//   col = colt*16 + (lane&15), k = k32*32 + (lane>>4)*8 + i
// One (colt,k32) tile = 512 shorts = 1KB; a wave's B-frag load = tile + lane*8.
__global__ void prep_w_k(const float* __restrict__ W1, const float* __restrict__ W2,
                         const float* __restrict__ We, const float* __restrict__ Wout,
                         unsigned short* __restrict__ W1t, unsigned short* __restrict__ W2t,
                         unsigned short* __restrict__ Wet, unsigned short* __restrict__ Ut) {
  const int SZW = J_TYPES * 65536;
  const int total = SZW * 2 + DE * DO + 3 * 65536;
  for (int o = blockIdx.x * blockDim.x + threadIdx.x; o < total;
       o += gridDim.x * blockDim.x) {
    int idx = o;
    if (idx < SZW) {                       // W1 frag-native, K=256
      int j = idx >> 16, r = idx & 65535;
      int i = r & 7, lane = (r >> 3) & 63, t = r >> 9;
      int k32 = t & 7, colt = t >> 3;
      int col = colt * 16 + (lane & 15);
      int k = k32 * 32 + ((lane >> 4) << 3) + i;
      W1t[idx] = f2bf(W1[((size_t)j * 256 + k) * 256 + col]);
    } else if ((idx -= SZW) < SZW) {       // W2
      int j = idx >> 16, r = idx & 65535;
      int i = r & 7, lane = (r >> 3) & 63, t = r >> 9;
      int k32 = t & 7, colt = t >> 3;
      int col = colt * 16 + (lane & 15);
      int k = k32 * 32 + ((lane >> 4) << 3) + i;
      W2t[idx] = f2bf(W2[((size_t)j * 256 + k) * 256 + col]);
    } else if ((idx -= SZW) < DE * DO) {   // We, K=128 (4 k32-tiles per colt)
      int r = idx;
      int i = r & 7, lane = (r >> 3) & 63, t = r >> 9;
      int k32 = t & 3, colt = t >> 2;
      int col = colt * 16 + (lane & 15);
      int k = k32 * 32 + ((lane >> 4) << 3) + i;
      Wet[idx] = f2bf(We[(size_t)k * 256 + col]);
    } else {                               // Wout (3 stacked K=256 matrices)
      idx -= DE * DO;
      int p = idx >> 16, r = idx & 65535;
      int i = r & 7, lane = (r >> 3) & 63, t = r >> 9;
      int k32 = t & 7, colt = t >> 3;
      int col = colt * 16 + (lane & 15);
      int k = k32 * 32 + ((lane >> 4) << 3) + i;
      Ut[idx] = f2bf(Wout[((size_t)p * 256 + k) * 256 + col]);
    }
  }
}

// ---------------- counting sort by pair ----------------
__global__ void hist_k(const int* __restrict__ ty1, const int* __restrict__ ty2,
                       int* __restrict__ cnt, int N) {
  __shared__ int h[PAIRS];
  for (int i = threadIdx.x; i < PAIRS; i += blockDim.x) h[i] = 0;
  __syncthreads();
  for (int i = blockIdx.x * blockDim.x + threadIdx.x; i < N;
       i += gridDim.x * blockDim.x)
    atomicAdd(&h[ty1[i] * J_TYPES + ty2[i]], 1);
  __syncthreads();
  for (int i = threadIdx.x; i < PAIRS; i += blockDim.x) {
    int v = h[i];
    if (v) atomicAdd(&cnt[i], v);
  }
}

__global__ void scan_tiles_k(const int* __restrict__ cnt, int* __restrict__ seg,
                             int* __restrict__ tpair, int* __restrict__ tstart,
                             int* __restrict__ tnr, int* __restrict__ ntl) {
  __shared__ int s1[512], s2[512];
  int t = threadIdx.x;                               // 512 threads
  int c  = (t < PAIRS) ? cnt[t] : 0;
  int nt = (c + TILE - 1) / TILE;
  s1[t] = c; s2[t] = nt;
  __syncthreads();
  for (int o = 1; o < 512; o <<= 1) {                // Hillis-Steele inclusive
    int v1 = (t >= o) ? s1[t - o] : 0;
    int v2 = (t >= o) ? s2[t - o] : 0;
    __syncthreads();
    s1[t] += v1; s2[t] += v2;
    __syncthreads();
  }
  if (t < PAIRS) {
    int segstart = s1[t] - c;
    int tbase    = s2[t] - nt;
    seg[t] = segstart;
    for (int i = 0; i < nt; ++i) {
      tpair[tbase + i]  = t;
      tstart[tbase + i] = segstart + i * TILE;
      int rem = c - i * TILE;
      tnr[tbase + i] = rem < TILE ? rem : TILE;
    }
  }
  if (t == 511) ntl[0] = s2[511];
}

// block-aggregated scatter: one global atomic per (block,pair)
__global__ void scatter_k(const int* __restrict__ ty1, const int* __restrict__ ty2,
                          const int* __restrict__ seg, int* __restrict__ c2,
                          int* __restrict__ ridx, int N) {
  __shared__ int lh[PAIRS], lb[PAIRS];
  int chunk = (N + gridDim.x - 1) / gridDim.x;
  int lo = blockIdx.x * chunk;
  int hi = lo + chunk; if (hi > N) hi = N;
  for (int i = threadIdx.x; i < PAIRS; i += blockDim.x) lh[i] = 0;
  __syncthreads();
  for (int i = lo + threadIdx.x; i < hi; i += blockDim.x)
    atomicAdd(&lh[ty1[i] * J_TYPES + ty2[i]], 1);
  __syncthreads();
  for (int i = threadIdx.x; i < PAIRS; i += blockDim.x) {
    int v = lh[i];
    lb[i] = v ? atomicAdd(&c2[i], v) : 0;
    lh[i] = 0;
  }
  __syncthreads();
  for (int i = lo + threadIdx.x; i < hi; i += blockDim.x) {
    int p = ty1[i] * J_TYPES + ty2[i];
    int pos = seg[p] + lb[p] + atomicAdd(&lh[p], 1);
    ridx[pos] = i;
  }
}

// ---------------- fused tile kernel ----------------
// 8 waves/block (512 thr), wave w owns cols [w*32, w*32+32) of tmp AND of out.
// A-frag: lane l -> row (l&15)+16rs, k=(l>>4)*8..+7 (b128 from LDS)
// B-frag: contiguous 1KB wave load from frag-native weights
// D-frag: col = l&15, row = (l>>4)*4 + reg

__device__ __forceinline__ void stage256(const float* __restrict__ src,
                                         const int* __restrict__ ridxp, int nrows,
                                         unsigned short* lds, int wave, int lane) {
  float4 f[8];
#pragma unroll
  for (int j = 0; j < 8; ++j) {
    int r = wave + 8 * j;
    int rc = r < nrows ? r : nrows - 1;          // uniform clamp
    int sr = ridxp[rc];                          // scalar load
    f[j] = reinterpret_cast<const float4*>(src + (size_t)sr * DN)[lane];
  }
#pragma unroll
  for (int j = 0; j < 8; ++j) {
    int r = wave + 8 * j;
    unsigned lo = cvtpk(f[j].x, f[j].y), hi = cvtpk(f[j].z, f[j].w);
    *reinterpret_cast<uint2*>(lds + r * LDA + lane * 4) = make_uint2(lo, hi);
  }
}

__device__ __forceinline__ void stage128(const float* __restrict__ src,
                                         const int* __restrict__ ridxp, int nrows,
                                         unsigned short* lds, int wave, int lane) {
  float2 f[8];
#pragma unroll
  for (int j = 0; j < 8; ++j) {
    int r = wave + 8 * j;
    int rc = r < nrows ? r : nrows - 1;
    int sr = ridxp[rc];
    f[j] = reinterpret_cast<const float2*>(src + (size_t)sr * DE)[lane];
  }
#pragma unroll
  for (int j = 0; j < 8; ++j) {
    int r = wave + 8 * j;
    *reinterpret_cast<unsigned*>(lds + r * LDE + lane * 2) = cvtpk(f[j].x, f[j].y);
  }
}

// cross-tile half-stage (4 rows held in regs; issue and write are separate)
__device__ __forceinline__ void issue256h(const float* __restrict__ src,
                                          const int* __restrict__ ridxp, int nrows,
                                          int wave, int lane, int h, float4 f[4]) {
#pragma unroll
  for (int j = 0; j < 4; ++j) {
    int r = wave + 8 * (h * 4 + j);
    int rc = r < nrows ? r : nrows - 1;
    int sr = ridxp[rc];
    f[j] = reinterpret_cast<const float4*>(src + (size_t)sr * DN)[lane];
  }
}

__device__ __forceinline__ void write256h(const float4 f[4], unsigned short* lds,
                                          int wave, int lane, int h) {
#pragma unroll
  for (int j = 0; j < 4; ++j) {
    int r = wave + 8 * (h * 4 + j);
    unsigned lo = cvtpk(f[j].x, f[j].y), hi = cvtpk(f[j].z, f[j].w);
    *reinterpret_cast<uint2*>(lds + r * LDA + lane * 4) = make_uint2(lo, hi);
  }
}

// Wave computes 64 rows x 32 cols over K = NK*32, per-wave k-stagger.
// B double-buffered (2-deep); A single-buffer (af-dbuf spills at this budget).
template <int NK, int LD>
__device__ __forceinline__ void gemm32(const unsigned short* lds,
                                       const unsigned short* __restrict__ Wbase,
                                       f32x4 acc[4][2], int r0, int kg, int lane,
                                       int wave) {
  const unsigned short* w = Wbase + ((size_t)(wave * 2) * NK) * 512 + lane * 8;
  const int kw = wave & (NK - 1);
  bf16x8 bf[2][2];
#pragma unroll
  for (int cs = 0; cs < 2; ++cs)
    bf[0][cs] = *reinterpret_cast<const bf16x8*>(w + ((size_t)cs * NK + kw) * 512);
#pragma unroll
  for (int i = 0; i < NK; ++i) {
    const int cur = i & 1, nxt = cur ^ 1;        // compile-time under full unroll
    const int kk = (i + wave) & (NK - 1);        // runtime-uniform, addr-only
    if (i + 1 < NK) {
      const int kk1 = (i + 1 + wave) & (NK - 1);
#pragma unroll
      for (int cs = 0; cs < 2; ++cs)
        bf[nxt][cs] =
            *reinterpret_cast<const bf16x8*>(w + ((size_t)cs * NK + kk1) * 512);
    }
    bf16x8 af[4];
#pragma unroll
    for (int rs = 0; rs < 4; ++rs)
      af[rs] = *reinterpret_cast<const bf16x8*>(lds + (rs * 16 + r0) * LD + kk * 32 + kg);
    __builtin_amdgcn_s_setprio(1);
#pragma unroll
    for (int rs = 0; rs < 4; ++rs)
#pragma unroll
      for (int cs = 0; cs < 2; ++cs)
        acc[rs][cs] = __builtin_amdgcn_mfma_f32_16x16x32_bf16(af[rs], bf[cur][cs],
                                                              acc[rs][cs], 0, 0, 0);
    __builtin_amdgcn_s_setprio(0);
  }
}

// epi: relu(accT + bias) -> bf16 -> ldsT (this wave's 32 cols)
__device__ __forceinline__ void epi32(f32x4 accT[4][2], const float* __restrict__ bias,
                                      unsigned short* ldsT, int r0, int rb, int wave) {
#pragma unroll
  for (int cs = 0; cs < 2; ++cs) {
    int col = wave * 32 + cs * 16 + r0;
    float b = bias[col];
#pragma unroll
    for (int rs = 0; rs < 4; ++rs) {
      float x0 = fmaxf(accT[rs][cs][0] + b, 0.f);
      float x1 = fmaxf(accT[rs][cs][1] + b, 0.f);
      float x2 = fmaxf(accT[rs][cs][2] + b, 0.f);
      float x3 = fmaxf(accT[rs][cs][3] + b, 0.f);
      unsigned w01 = cvtpk(x0, x1), w23 = cvtpk(x2, x3);
      int row = rs * 16 + rb;
      ldsT[(row + 0) * LDA + col] = (unsigned short)w01;
      ldsT[(row + 1) * LDA + col] = (unsigned short)(w01 >> 16);
      ldsT[(row + 2) * LDA + col] = (unsigned short)w23;
      ldsT[(row + 3) * LDA + col] = (unsigned short)(w23 >> 16);
    }
  }
}

#define ZERO42(A)                                                        \
  _Pragma("unroll") for (int a_ = 0; a_ < 4; ++a_) _Pragma("unroll")     \
      for (int b_ = 0; b_ < 2; ++b_) A[a_][b_] = (f32x4){0.f, 0.f, 0.f, 0.f};

__global__ __launch_bounds__(512, 4) void fused_k(
    const float* __restrict__ n1, const float* __restrict__ n2,
    const float* __restrict__ eg, const unsigned short* __restrict__ W1t,
    const unsigned short* __restrict__ W2t, const unsigned short* __restrict__ Wet,
    const unsigned short* __restrict__ Ut, const float* __restrict__ b1,
    const float* __restrict__ b2, const float* __restrict__ be,
    const float* __restrict__ bout, const int* __restrict__ ridx,
    const int* __restrict__ tpair, const int* __restrict__ tstart,
    const int* __restrict__ tnr, const int* __restrict__ ntl,
    float* __restrict__ out) {
  const int ntiles = ntl[0];
  // XCD-chunked contiguous tile ranges: blocks on XCD x own chunks [x*64,(x+1)*64)
  const int cidx = (blockIdx.x & 7) * (NBLK / 8) + (blockIdx.x >> 3);
  const int chunk = (ntiles + NBLK - 1) / NBLK;
  const int lo = cidx * chunk;
  const int hi = min(lo + chunk, ntiles);
  if (lo >= hi) return;

  __shared__ unsigned short ldsA[TILE * LDA];
  __shared__ unsigned short ldsT[TILE * LDA];
  __shared__ int srow[2][TILE];

  const int lane = threadIdx.x & 63;
  const int wave = __builtin_amdgcn_readfirstlane(threadIdx.x >> 6);
  const int r0 = lane & 15;
  const int kg = (lane >> 4) * 8;
  const int rb = (lane >> 4) * 4;

  f32x4 accT[4][2], accO[4][2];
  float4 fa[4];

  // ---- prologue: meta + srow + stage n1 for first tile
  int pr = tpair[lo];
  int nrows = tnr[lo];
  const int* ridxp = ridx + tstart[lo];
  if (threadIdx.x < TILE) {
    int rc = threadIdx.x < nrows ? threadIdx.x : nrows - 1;
    srow[lo & 1][threadIdx.x] = ridxp[rc];
  }
  stage256(n1, ridxp, nrows, ldsA, wave, lane);

  for (int t = lo; t < hi; ++t) {
    const int t1 = pr / J_TYPES, t2 = pr % J_TYPES;
    BAR();   // n1(t) in ldsA + srow visible

    // ---- Y0: gemm1(n1)
    ZERO42(accT);
    gemm32<8, LDA>(ldsA, W1t + (size_t)t1 * 65536, accT, r0, kg, lane, wave);
    BAR();

    // ---- X0: epi(0) -> ldsT ; stage n2 -> ldsA
    epi32(accT, b1 + t1 * 256, ldsT, r0, rb, wave);
    stage256(n2, ridxp, nrows, ldsA, wave, lane);
    BAR();

    // ---- Y1: gemm2(0) + gemm1(n2)
    ZERO42(accO);
    gemm32<8, LDA>(ldsT, Ut, accO, r0, kg, lane, wave);
    ZERO42(accT);
    gemm32<8, LDA>(ldsA, W2t + (size_t)t2 * 65536, accT, r0, kg, lane, wave);
    BAR();

    // ---- X1: epi(1) -> ldsT ; stage edge -> ldsA
    epi32(accT, b2 + t2 * 256, ldsT, r0, rb, wave);
    stage128(eg, ridxp, nrows, ldsA, wave, lane);
    BAR();

    // ---- Y2: gemm2(1) + gemm1(edge)
    gemm32<8, LDA>(ldsT, Ut + 65536, accO, r0, kg, lane, wave);
    ZERO42(accT);
    gemm32<4, LDE>(ldsA, Wet, accT, r0, kg, lane, wave);
    BAR();

    // ---- X2: epi(edge) -> ldsT ; next-tile meta + srow + issue n1 half0
    epi32(accT, be, ldsT, r0, rb, wave);
    const bool more = (t + 1 < hi);
    int pr_n = pr, nrows_n = nrows;
    const int* ridxp_n = ridxp;
    if (more) {
      pr_n = tpair[t + 1];
      nrows_n = tnr[t + 1];
      ridxp_n = ridx + tstart[t + 1];
      if (threadIdx.x < TILE) {
        int rc = threadIdx.x < nrows_n ? threadIdx.x : nrows_n - 1;
        srow[(t + 1) & 1][threadIdx.x] = ridxp_n[rc];
      }
      issue256h(n1, ridxp_n, nrows_n, wave, lane, 0, fa);   // floats across BAR
    }
    BAR();

    // ---- Y3: gemm2(edge) ; write n1.h0 ; issue n1.h1 ; epilogue ; write n1.h1
    gemm32<8, LDA>(ldsT, Ut + 2 * 65536, accO, r0, kg, lane, wave);
    if (more) {
      write256h(fa, ldsA, wave, lane, 0);                   // ldsA free since X2 BAR
      issue256h(n1, ridxp_n, nrows_n, wave, lane, 1, fa);   // latency hidden by epilogue
    }

    // epilogue: relu(accO + bout) -> scattered rows (srow of CURRENT tile)
    const int* sp = srow[t & 1];
#pragma unroll
    for (int cs = 0; cs < 2; ++cs) {
      int col = wave * 32 + cs * 16 + r0;
      float bo = bout[col];
#pragma unroll
      for (int rs = 0; rs < 4; ++rs)
#pragma unroll
        for (int i = 0; i < 4; ++i) {
          int row = rs * 16 + rb + i;
          if (row < nrows) {
            float v = fmaxf(accO[rs][cs][i] + bo, 0.f);
            out[(size_t)sp[row] * 256 + col] = v;
          }
        }
    }
    if (more) write256h(fa, ldsA, wave, lane, 1);

    pr = pr_n; nrows = nrows_n; ridxp = ridxp_n;
  }
}

// ---------------- launcher ----------------
extern "C" void kernel_launch(void* const* d_in, const int* in_sizes, int n_in,
                              void* d_out, int out_size, void* d_ws, size_t ws_size,
                              hipStream_t stream) {
  const float* n1   = (const float*)d_in[0];
  const float* n2   = (const float*)d_in[1];
  const float* eg   = (const float*)d_in[2];
  const int*   ty1  = (const int*)d_in[3];
  const int*   ty2  = (const int*)d_in[4];
  const float* W1   = (const float*)d_in[5];
  const float* b1   = (const float*)d_in[6];
  const float* W2   = (const float*)d_in[7];
  const float* b2   = (const float*)d_in[8];
  const float* We   = (const float*)d_in[9];
  const float* be   = (const float*)d_in[10];
  const float* Wout = (const float*)d_in[11];
  const float* bout = (const float*)d_in[12];
  float* out = (float*)d_out;

  const int N = in_sizes[0] / DN;
  const int maxt = (N + TILE - 1) / TILE + PAIRS;

  char* ws = (char*)d_ws;
  size_t off = 0;
  auto take = [&](size_t bytes) -> char* {
    char* p = ws + off;
    off += (bytes + 255) & ~(size_t)255;
    return p;
  };
  int* cnt = (int*)take(PAIRS * 4);
  int* c2  = (int*)take(PAIRS * 4);
  int* ntl = (int*)take(4);
  int* seg = (int*)take((PAIRS + 1) * 4);
  int* tp  = (int*)take((size_t)maxt * 4);
  int* tst = (int*)take((size_t)maxt * 4);
  int* tnr = (int*)take((size_t)maxt * 4);
  int* ridx = (int*)take((size_t)N * 4);
  unsigned short* W1t = (unsigned short*)take((size_t)J_TYPES * 65536 * 2);
  unsigned short* W2t = (unsigned short*)take((size_t)J_TYPES * 65536 * 2);
  unsigned short* Wet = (unsigned short*)take((size_t)DE * DO * 2);
  unsigned short* Ut  = (unsigned short*)take((size_t)3 * 65536 * 2);
  (void)ws_size; (void)n_in; (void)out_size;

  hipMemsetAsync(cnt, 0, (size_t)((char*)seg - (char*)cnt), stream);
  prep_w_k<<<1024, 256, 0, stream>>>(W1, W2, We, Wout, W1t, W2t, Wet, Ut);
  hist_k<<<400, 256, 0, stream>>>(ty1, ty2, cnt, N);
  scan_tiles_k<<<1, 512, 0, stream>>>(cnt, seg, tp, tst, tnr, ntl);
  scatter_k<<<256, 256, 0, stream>>>(ty1, ty2, seg, c2, ridx, N);
  fused_k<<<NBLK, 512, 0, stream>>>(n1, n2, eg, W1t, W2t, Wet, Ut, b1, b2, be, bout,
                                    ridx, tp, tst, tnr, ntl, out);
}

// Round 12
// 289.306 us; speedup vs baseline: 1.9834x; 1.9834x over previous
//
#include <hip/hip_runtime.h>

// TypeAwareEdgeUpdate: out = relu(relu(cat[n1@W1[t1]+b1, n2@W2[t2]+b2, e@We+be]) @ Wout + bout)
// Counting-sort rows by (t1,t2) -> 64-row tiles share weights -> fused bf16 MFMA.
// R12 = R7 verbatim (best measured: 290us). 8 waves x 32 cols (512 thr), 2 blocks/CU
// (4 waves/SIMD), per-wave k-stagger, 2-deep B dbuf, lgkm-only barriers, setprio.
// R8-R11 (af-dbuf / 1-blk pipeline / half-split stage / persistent prefetch) all
// regressed: register file is exactly full (64 acc + 64 arch = 128/wave) -> any
// held staging state spills; occupancy drops lose more than pipelining gains.

#define J_TYPES 17
#define PAIRS   (J_TYPES * J_TYPES)
#define DN      256
#define DE      128
#define DO      256
#define TILE    64
#define LDA     264   // ldsA / ldsT stride (shorts) for 256 cols
#define LDE     136   // ldsA stride for K=128 (edge path)

typedef short bf16x8 __attribute__((ext_vector_type(8)));
typedef float f32x4  __attribute__((ext_vector_type(4)));

// LDS-only barrier: wait LDS ops, let VMEM stay in flight across it.
#define BAR() asm volatile("s_waitcnt lgkmcnt(0)\n\ts_barrier" ::: "memory")

__device__ __forceinline__ unsigned short f2bf(float x) {
  unsigned u = __float_as_uint(x);
  return (unsigned short)((u + 0x7fffu + ((u >> 16) & 1u)) >> 16);  // RNE
}

__device__ __forceinline__ unsigned cvtpk(float lo, float hi) {
  unsigned r;
  asm("v_cvt_pk_bf16_f32 %0, %1, %2" : "=v"(r) : "v"(lo), "v"(hi));
  return r;  // lo16 = bf16(lo), hi16 = bf16(hi), RNE
}

// ---------------- weight prep: bf16, fragment-native layout ----------------
// Layout per matrix: [colt][k32][lane][i] (shorts), element (col,k):
//   col = colt*16 + (lane&15), k = k32*32 + (lane>>4)*8 + i
// One (colt,k32) tile = 512 shorts = 1KB; a wave's B-frag load = tile + lane*8.
__global__ void prep_w_k(const float* __restrict__ W1, const float* __restrict__ W2,
                         const float* __restrict__ We, const float* __restrict__ Wout,
                         unsigned short* __restrict__ W1t, unsigned short* __restrict__ W2t,
                         unsigned short* __restrict__ Wet, unsigned short* __restrict__ Ut) {
  const int SZW = J_TYPES * 65536;
  const int total = SZW * 2 + DE * DO + 3 * 65536;
  for (int o = blockIdx.x * blockDim.x + threadIdx.x; o < total;
       o += gridDim.x * blockDim.x) {
    int idx = o;
    if (idx < SZW) {                       // W1 frag-native, K=256
      int j = idx >> 16, r = idx & 65535;
      int i = r & 7, lane = (r >> 3) & 63, t = r >> 9;
      int k32 = t & 7, colt = t >> 3;
      int col = colt * 16 + (lane & 15);
      int k = k32 * 32 + ((lane >> 4) << 3) + i;
      W1t[idx] = f2bf(W1[((size_t)j * 256 + k) * 256 + col]);
    } else if ((idx -= SZW) < SZW) {       // W2
      int j = idx >> 16, r = idx & 65535;
      int i = r & 7, lane = (r >> 3) & 63, t = r >> 9;
      int k32 = t & 7, colt = t >> 3;
      int col = colt * 16 + (lane & 15);
      int k = k32 * 32 + ((lane >> 4) << 3) + i;
      W2t[idx] = f2bf(W2[((size_t)j * 256 + k) * 256 + col]);
    } else if ((idx -= SZW) < DE * DO) {   // We, K=128 (4 k32-tiles per colt)
      int r = idx;
      int i = r & 7, lane = (r >> 3) & 63, t = r >> 9;
      int k32 = t & 3, colt = t >> 2;
      int col = colt * 16 + (lane & 15);
      int k = k32 * 32 + ((lane >> 4) << 3) + i;
      Wet[idx] = f2bf(We[(size_t)k * 256 + col]);
    } else {                               // Wout (3 stacked K=256 matrices)
      idx -= DE * DO;
      int p = idx >> 16, r = idx & 65535;
      int i = r & 7, lane = (r >> 3) & 63, t = r >> 9;
      int k32 = t & 7, colt = t >> 3;
      int col = colt * 16 + (lane & 15);
      int k = k32 * 32 + ((lane >> 4) << 3) + i;
      Ut[idx] = f2bf(Wout[((size_t)p * 256 + k) * 256 + col]);
    }
  }
}

// ---------------- counting sort by pair ----------------
__global__ void hist_k(const int* __restrict__ ty1, const int* __restrict__ ty2,
                       int* __restrict__ cnt, int N) {
  __shared__ int h[PAIRS];
  for (int i = threadIdx.x; i < PAIRS; i += blockDim.x) h[i] = 0;
  __syncthreads();
  for (int i = blockIdx.x * blockDim.x + threadIdx.x; i < N;
       i += gridDim.x * blockDim.x)
    atomicAdd(&h[ty1[i] * J_TYPES + ty2[i]], 1);
  __syncthreads();
  for (int i = threadIdx.x; i < PAIRS; i += blockDim.x) {
    int v = h[i];
    if (v) atomicAdd(&cnt[i], v);
  }
}

__global__ void scan_tiles_k(const int* __restrict__ cnt, int* __restrict__ seg,
                             int* __restrict__ tpair, int* __restrict__ tstart,
                             int* __restrict__ tnr, int* __restrict__ ntl) {
  __shared__ int s1[512], s2[512];
  int t = threadIdx.x;                               // 512 threads
  int c  = (t < PAIRS) ? cnt[t] : 0;
  int nt = (c + TILE - 1) / TILE;
  s1[t] = c; s2[t] = nt;
  __syncthreads();
  for (int o = 1; o < 512; o <<= 1) {                // Hillis-Steele inclusive
    int v1 = (t >= o) ? s1[t - o] : 0;
    int v2 = (t >= o) ? s2[t - o] : 0;
    __syncthreads();
    s1[t] += v1; s2[t] += v2;
    __syncthreads();
  }
  if (t < PAIRS) {
    int segstart = s1[t] - c;
    int tbase    = s2[t] - nt;
    seg[t] = segstart;
    for (int i = 0; i < nt; ++i) {
      tpair[tbase + i]  = t;
      tstart[tbase + i] = segstart + i * TILE;
      int rem = c - i * TILE;
      tnr[tbase + i] = rem < TILE ? rem : TILE;
    }
  }
  if (t == 511) ntl[0] = s2[511];
}

// block-aggregated scatter: one global atomic per (block,pair)
__global__ void scatter_k(const int* __restrict__ ty1, const int* __restrict__ ty2,
                          const int* __restrict__ seg, int* __restrict__ c2,
                          int* __restrict__ ridx, int N) {
  __shared__ int lh[PAIRS], lb[PAIRS];
  int chunk = (N + gridDim.x - 1) / gridDim.x;
  int lo = blockIdx.x * chunk;
  int hi = lo + chunk; if (hi > N) hi = N;
  for (int i = threadIdx.x; i < PAIRS; i += blockDim.x) lh[i] = 0;
  __syncthreads();
  for (int i = lo + threadIdx.x; i < hi; i += blockDim.x)
    atomicAdd(&lh[ty1[i] * J_TYPES + ty2[i]], 1);
  __syncthreads();
  for (int i = threadIdx.x; i < PAIRS; i += blockDim.x) {
    int v = lh[i];
    lb[i] = v ? atomicAdd(&c2[i], v) : 0;
    lh[i] = 0;
  }
  __syncthreads();
  for (int i = lo + threadIdx.x; i < hi; i += blockDim.x) {
    int p = ty1[i] * J_TYPES + ty2[i];
    int pos = seg[p] + lb[p] + atomicAdd(&lh[p], 1);
    ridx[pos] = i;
  }
}

// ---------------- fused tile kernel ----------------
// 8 waves/block (512 thr), wave w owns cols [w*32, w*32+32) of tmp AND of out.
// A-frag: lane l -> row (l&15)+16rs, k=(l>>4)*8..+7 (b128 from LDS)
// B-frag: contiguous 1KB wave load from frag-native weights
// D-frag: col = l&15, row = (l>>4)*4 + reg

__device__ __forceinline__ void stage256(const float* __restrict__ src,
                                         const int* __restrict__ ridxp, int nrows,
                                         unsigned short* lds, int wave, int lane) {
  float4 f[8];
#pragma unroll
  for (int j = 0; j < 8; ++j) {
    int r = wave + 8 * j;
    int rc = r < nrows ? r : nrows - 1;          // uniform clamp
    int sr = ridxp[rc];                          // scalar load
    f[j] = reinterpret_cast<const float4*>(src + (size_t)sr * DN)[lane];
  }
#pragma unroll
  for (int j = 0; j < 8; ++j) {
    int r = wave + 8 * j;
    unsigned lo = cvtpk(f[j].x, f[j].y), hi = cvtpk(f[j].z, f[j].w);
    *reinterpret_cast<uint2*>(lds + r * LDA + lane * 4) = make_uint2(lo, hi);
  }
}

__device__ __forceinline__ void stage128(const float* __restrict__ src,
                                         const int* __restrict__ ridxp, int nrows,
                                         unsigned short* lds, int wave, int lane) {
  float2 f[8];
#pragma unroll
  for (int j = 0; j < 8; ++j) {
    int r = wave + 8 * j;
    int rc = r < nrows ? r : nrows - 1;
    int sr = ridxp[rc];
    f[j] = reinterpret_cast<const float2*>(src + (size_t)sr * DE)[lane];
  }
#pragma unroll
  for (int j = 0; j < 8; ++j) {
    int r = wave + 8 * j;
    *reinterpret_cast<unsigned*>(lds + r * LDE + lane * 2) = cvtpk(f[j].x, f[j].y);
  }
}

// Wave computes 64 rows x 32 cols over K = NK*32, with per-wave k-stagger:
// wave w starts at k32=(w & NK-1) so co-resident waves hit different pipe stages.
// 2-deep B double-buffer (static indices under full unroll).
template <int NK, int LD>
__device__ __forceinline__ void gemm32(const unsigned short* lds,
                                       const unsigned short* __restrict__ Wbase,
                                       f32x4 acc[4][2], int r0, int kg, int lane,
                                       int wave) {
  const unsigned short* w = Wbase + ((size_t)(wave * 2) * NK) * 512 + lane * 8;
  const int kw = wave & (NK - 1);
  bf16x8 bf[2][2];
#pragma unroll
  for (int cs = 0; cs < 2; ++cs)
    bf[0][cs] = *reinterpret_cast<const bf16x8*>(w + ((size_t)cs * NK + kw) * 512);
#pragma unroll
  for (int i = 0; i < NK; ++i) {
    const int cur = i & 1, nxt = cur ^ 1;        // compile-time under full unroll
    const int kk = (i + wave) & (NK - 1);        // runtime-uniform, addr-only
    if (i + 1 < NK) {
      const int kk1 = (i + 1 + wave) & (NK - 1);
#pragma unroll
      for (int cs = 0; cs < 2; ++cs)
        bf[nxt][cs] =
            *reinterpret_cast<const bf16x8*>(w + ((size_t)cs * NK + kk1) * 512);
    }
    bf16x8 af[4];
#pragma unroll
    for (int rs = 0; rs < 4; ++rs)
      af[rs] = *reinterpret_cast<const bf16x8*>(lds + (rs * 16 + r0) * LD + kk * 32 + kg);
    __builtin_amdgcn_s_setprio(1);
#pragma unroll
    for (int rs = 0; rs < 4; ++rs)
#pragma unroll
      for (int cs = 0; cs < 2; ++cs)
        acc[rs][cs] = __builtin_amdgcn_mfma_f32_16x16x32_bf16(af[rs], bf[cur][cs],
                                                              acc[rs][cs], 0, 0, 0);
    __builtin_amdgcn_s_setprio(0);
  }
}

// epi: relu(accT + bias) -> bf16 -> ldsT (this wave's 32 cols)
__device__ __forceinline__ void epi32(f32x4 accT[4][2], const float* __restrict__ bias,
                                      unsigned short* ldsT, int r0, int rb, int wave) {
#pragma unroll
  for (int cs = 0; cs < 2; ++cs) {
    int col = wave * 32 + cs * 16 + r0;
    float b = bias[col];
#pragma unroll
    for (int rs = 0; rs < 4; ++rs) {
      float x0 = fmaxf(accT[rs][cs][0] + b, 0.f);
      float x1 = fmaxf(accT[rs][cs][1] + b, 0.f);
      float x2 = fmaxf(accT[rs][cs][2] + b, 0.f);
      float x3 = fmaxf(accT[rs][cs][3] + b, 0.f);
      unsigned w01 = cvtpk(x0, x1), w23 = cvtpk(x2, x3);
      int row = rs * 16 + rb;
      ldsT[(row + 0) * LDA + col] = (unsigned short)w01;
      ldsT[(row + 1) * LDA + col] = (unsigned short)(w01 >> 16);
      ldsT[(row + 2) * LDA + col] = (unsigned short)w23;
      ldsT[(row + 3) * LDA + col] = (unsigned short)(w23 >> 16);
    }
  }
}

#define ZERO42(A)                                                        \
  _Pragma("unroll") for (int a_ = 0; a_ < 4; ++a_) _Pragma("unroll")     \
      for (int b_ = 0; b_ < 2; ++b_) A[a_][b_] = (f32x4){0.f, 0.f, 0.f, 0.f};

__global__ __launch_bounds__(512, 4) void fused_k(
    const float* __restrict__ n1, const float* __restrict__ n2,
    const float* __restrict__ eg, const unsigned short* __restrict__ W1t,
    const unsigned short* __restrict__ W2t, const unsigned short* __restrict__ Wet,
    const unsigned short* __restrict__ Ut, const float* __restrict__ b1,
    const float* __restrict__ b2, const float* __restrict__ be,
    const float* __restrict__ bout, const int* __restrict__ ridx,
    const int* __restrict__ tpair, const int* __restrict__ tstart,
    const int* __restrict__ tnr, const int* __restrict__ ntl,
    float* __restrict__ out) {
  // bijective XCD swizzle: same-pair tiles (consecutive) -> same XCD's L2
  int nwg = gridDim.x, orig = blockIdx.x;
  int q = nwg >> 3, rr = nwg & 7, xc = orig & 7, sidx = orig >> 3;
  int tile = (xc < rr ? xc * (q + 1) : rr * (q + 1) + (xc - rr) * q) + sidx;
  if (tile >= ntl[0]) return;

  const int pr = tpair[tile];
  const int t1 = pr / J_TYPES, t2 = pr % J_TYPES;
  const int ts = tstart[tile];
  const int nrows = tnr[tile];
  const int* __restrict__ ridxp = ridx + ts;

  __shared__ unsigned short ldsA[TILE * LDA];
  __shared__ unsigned short ldsT[TILE * LDA];
  __shared__ int srow[TILE];

  const int lane = threadIdx.x & 63;
  const int wave = __builtin_amdgcn_readfirstlane(threadIdx.x >> 6);
  const int r0 = lane & 15;
  const int kg = (lane >> 4) * 8;
  const int rb = (lane >> 4) * 4;

  if (threadIdx.x < TILE)
    srow[threadIdx.x] = (threadIdx.x < nrows) ? ridxp[threadIdx.x] : -1;
  // srow read only in final epilogue (barriers between)

  f32x4 accT[4][2], accO[4][2];

  // ---- P: stage n1
  stage256(n1, ridxp, nrows, ldsA, wave, lane);
  BAR();

  // ---- Y0: gemm1(n1)
  ZERO42(accT);
  gemm32<8, LDA>(ldsA, W1t + (size_t)t1 * 65536, accT, r0, kg, lane, wave);
  BAR();

  // ---- X0: epi(0) -> ldsT ; stage n2 -> ldsA
  epi32(accT, b1 + t1 * 256, ldsT, r0, rb, wave);
  stage256(n2, ridxp, nrows, ldsA, wave, lane);
  BAR();

  // ---- Y1: gemm2(0) + gemm1(n2)
  ZERO42(accO);
  gemm32<8, LDA>(ldsT, Ut, accO, r0, kg, lane, wave);
  ZERO42(accT);
  gemm32<8, LDA>(ldsA, W2t + (size_t)t2 * 65536, accT, r0, kg, lane, wave);
  BAR();

  // ---- X1: epi(1) -> ldsT ; stage edge -> ldsA
  epi32(accT, b2 + t2 * 256, ldsT, r0, rb, wave);
  stage128(eg, ridxp, nrows, ldsA, wave, lane);
  BAR();

  // ---- Y2: gemm2(1) + gemm1(edge)
  gemm32<8, LDA>(ldsT, Ut + 65536, accO, r0, kg, lane, wave);
  ZERO42(accT);
  gemm32<4, LDE>(ldsA, Wet, accT, r0, kg, lane, wave);
  BAR();

  // ---- X2: epi(edge) -> ldsT
  epi32(accT, be, ldsT, r0, rb, wave);
  BAR();

  // ---- Y3: gemm2(edge)
  gemm32<8, LDA>(ldsT, Ut + 2 * 65536, accO, r0, kg, lane, wave);

  // ---- epilogue: relu(accO + bout) -> scattered rows
#pragma unroll
  for (int cs = 0; cs < 2; ++cs) {
    int col = wave * 32 + cs * 16 + r0;
    float bo = bout[col];
#pragma unroll
    for (int rs = 0; rs < 4; ++rs)
#pragma unroll
      for (int i = 0; i < 4; ++i) {
        int row = rs * 16 + rb + i;
        if (row < nrows) {
          float v = fmaxf(accO[rs][cs][i] + bo, 0.f);
          out[(size_t)srow[row] * 256 + col] = v;
        }
      }
  }
}

// ---------------- launcher ----------------
extern "C" void kernel_launch(void* const* d_in, const int* in_sizes, int n_in,
                              void* d_out, int out_size, void* d_ws, size_t ws_size,
                              hipStream_t stream) {
  const float* n1   = (const float*)d_in[0];
  const float* n2   = (const float*)d_in[1];
  const float* eg   = (const float*)d_in[2];
  const int*   ty1  = (const int*)d_in[3];
  const int*   ty2  = (const int*)d_in[4];
  const float* W1   = (const float*)d_in[5];
  const float* b1   = (const float*)d_in[6];
  const float* W2   = (const float*)d_in[7];
  const float* b2   = (const float*)d_in[8];
  const float* We   = (const float*)d_in[9];
  const float* be   = (const float*)d_in[10];
  const float* Wout = (const float*)d_in[11];
  const float* bout = (const float*)d_in[12];
  float* out = (float*)d_out;

  const int N = in_sizes[0] / DN;
  const int maxt = (N + TILE - 1) / TILE + PAIRS;

  char* ws = (char*)d_ws;
  size_t off = 0;
  auto take = [&](size_t bytes) -> char* {
    char* p = ws + off;
    off += (bytes + 255) & ~(size_t)255;
    return p;
  };
  int* cnt = (int*)take(PAIRS * 4);
  int* c2  = (int*)take(PAIRS * 4);
  int* ntl = (int*)take(4);
  int* seg = (int*)take((PAIRS + 1) * 4);
  int* tp  = (int*)take((size_t)maxt * 4);
  int* tst = (int*)take((size_t)maxt * 4);
  int* tnr = (int*)take((size_t)maxt * 4);
  int* ridx = (int*)take((size_t)N * 4);
  unsigned short* W1t = (unsigned short*)take((size_t)J_TYPES * 65536 * 2);
  unsigned short* W2t = (unsigned short*)take((size_t)J_TYPES * 65536 * 2);
  unsigned short* Wet = (unsigned short*)take((size_t)DE * DO * 2);
  unsigned short* Ut  = (unsigned short*)take((size_t)3 * 65536 * 2);
  (void)ws_size; (void)n_in; (void)out_size;

  hipMemsetAsync(cnt, 0, (size_t)((char*)seg - (char*)cnt), stream);
  prep_w_k<<<1024, 256, 0, stream>>>(W1, W2, We, Wout, W1t, W2t, Wet, Ut);
  hist_k<<<400, 256, 0, stream>>>(ty1, ty2, cnt, N);
  scan_tiles_k<<<1, 512, 0, stream>>>(cnt, seg, tp, tst, tnr, ntl);
  scatter_k<<<256, 256, 0, stream>>>(ty1, ty2, seg, c2, ridx, N);
  fused_k<<<maxt, 512, 0, stream>>>(n1, n2, eg, W1t, W2t, Wet, Ut, b1, b2, be, bout,
                                    ridx, tp, tst, tnr, ntl, out);
}